// Round 2
// baseline (457.070 us; speedup 1.0000x reference)
//
#include <hip/hip_runtime.h>
#include <cstdint>
#include <cstddef>

#define TB 2048
#define TE 128
#define TL 77
#define TW 64
#define TDI 128
#define TDS 16

// ---------- helpers ----------
__device__ __forceinline__ float bf2f(unsigned short h) {
    unsigned int u = ((unsigned int)h) << 16;
    float f; __builtin_memcpy(&f, &u, 4); return f;
}
__device__ __forceinline__ unsigned short f2bf(float f) {
    unsigned int u; __builtin_memcpy(&u, &f, 4);
    u = (u + 0x7fffu + ((u >> 16) & 1u)) >> 16;
    return (unsigned short)u;
}
__device__ __forceinline__ float bflo(unsigned int u) {
    unsigned int v = u << 16; float f; __builtin_memcpy(&f, &v, 4); return f;
}
__device__ __forceinline__ float bfhi(unsigned int u) {
    unsigned int v = u & 0xffff0000u; float f; __builtin_memcpy(&f, &v, 4); return f;
}
__device__ __forceinline__ float fast_rcp(float x) { return __builtin_amdgcn_rcpf(x); }
__device__ __forceinline__ float fsig(float x) { return fast_rcp(1.0f + __expf(-x)); }

// =====================================================================
// KA: x = enc @ dec_w.T + dec_b  (per 64-batch x one-l tile), then
//     xz = x @ in_w.T  -> u_raw (bf16), z (bf16).  x stays in LDS.
// =====================================================================
__global__ __launch_bounds__(256, 2)
void ka_dec_inproj(const float* __restrict__ enc,
                   const float* __restrict__ dec_w,
                   const float* __restrict__ dec_b,
                   const float* __restrict__ in_w,
                   unsigned short* __restrict__ u_raw,
                   unsigned short* __restrict__ z_out)
{
    __shared__ float smA[128 * 68];   // enc^T   [k][m], stride 68
    __shared__ float smB[128 * 68];   // dec_w^T [k][w], stride 68

    const int tid = threadIdx.x;
    const int m0  = blockIdx.x * 64;
    const int l   = blockIdx.y;

    // ---- stage (transpose) enc tile and dec_w tile into LDS
    {
        const int m  = tid >> 2;   // 0..63 (row within tile)
        const int kq = tid & 3;    // 0..3
        const float* encp = enc   + (size_t)(m0 + m) * TE;
        const float* dwp  = dec_w + (size_t)(l * 64 + m) * TE;
        #pragma unroll
        for (int i = 0; i < 8; ++i) {
            const int k4 = kq + 4 * i;                  // 0..31
            const float4 a = *(const float4*)(encp + k4 * 4);
            const float4 b = *(const float4*)(dwp  + k4 * 4);
            smA[(k4*4+0)*68 + m] = a.x; smA[(k4*4+1)*68 + m] = a.y;
            smA[(k4*4+2)*68 + m] = a.z; smA[(k4*4+3)*68 + m] = a.w;
            smB[(k4*4+0)*68 + m] = b.x; smB[(k4*4+1)*68 + m] = b.y;
            smB[(k4*4+2)*68 + m] = b.z; smB[(k4*4+3)*68 + m] = b.w;
        }
    }
    __syncthreads();

    // ---- GEMM1: x[m][w] = sum_k enc[m][k] * dec_w[l*64+w][k]
    const int tm = tid >> 4;   // 0..15
    const int tn = tid & 15;   // 0..15
    float acc[4][4];
    #pragma unroll
    for (int i = 0; i < 4; ++i)
        #pragma unroll
        for (int j = 0; j < 4; ++j) acc[i][j] = 0.f;

    #pragma unroll 4
    for (int k = 0; k < 128; ++k) {
        const float4 av = *(const float4*)&smA[k*68 + tm*4];
        const float4 bv = *(const float4*)&smB[k*68 + tn*4];
        const float aa[4] = {av.x, av.y, av.z, av.w};
        const float bb[4] = {bv.x, bv.y, bv.z, bv.w};
        #pragma unroll
        for (int i = 0; i < 4; ++i)
            #pragma unroll
            for (int j = 0; j < 4; ++j)
                acc[i][j] = fmaf(aa[i], bb[j], acc[i][j]);
    }
    __syncthreads();   // everyone done reading smA/smB

    // ---- overlay: Xs = x^T [w][m] (in smA), Ws = in_w bf16 [w][c] (in smB)
    float* Xs = smA;                            // [64][68]
    unsigned short* Ws = (unsigned short*)smB;  // [64][264]
    #pragma unroll
    for (int j = 0; j < 4; ++j) {
        const float bb = dec_b[l*64 + tn*4 + j];
        #pragma unroll
        for (int i = 0; i < 4; ++i)
            Xs[(tn*4+j)*68 + (tm*4+i)] = acc[i][j] + bb;
    }
    for (int idx = tid; idx < 256*64; idx += 256) {
        const int c = idx >> 6, w = idx & 63;   // in_w[c][w]
        Ws[w*264 + c] = f2bf(in_w[idx]);
    }
    __syncthreads();

    // ---- in_proj: xz[m][c] = sum_w x[m][w] * in_w[c][w]
    const int mq = tid >> 4;       // m0t = mq*4
    const int cq = tid & 15;       // c0  = cq*16
    const int c0 = cq * 16;
    float acc2[4][16];
    #pragma unroll
    for (int i = 0; i < 4; ++i)
        #pragma unroll
        for (int j = 0; j < 16; ++j) acc2[i][j] = 0.f;

    for (int w = 0; w < 64; ++w) {
        const float4 xv = *(const float4*)&Xs[w*68 + mq*4];
        const uint4 wa  = *(const uint4*)&Ws[w*264 + c0];
        const uint4 wb  = *(const uint4*)&Ws[w*264 + c0 + 8];
        float wf[16];
        wf[0]=bflo(wa.x);  wf[1]=bfhi(wa.x);  wf[2]=bflo(wa.y);  wf[3]=bfhi(wa.y);
        wf[4]=bflo(wa.z);  wf[5]=bfhi(wa.z);  wf[6]=bflo(wa.w);  wf[7]=bfhi(wa.w);
        wf[8]=bflo(wb.x);  wf[9]=bfhi(wb.x);  wf[10]=bflo(wb.y); wf[11]=bfhi(wb.y);
        wf[12]=bflo(wb.z); wf[13]=bfhi(wb.z); wf[14]=bflo(wb.w); wf[15]=bfhi(wb.w);
        const float xs4[4] = {xv.x, xv.y, xv.z, xv.w};
        #pragma unroll
        for (int i = 0; i < 4; ++i)
            #pragma unroll
            for (int j = 0; j < 16; ++j)
                acc2[i][j] = fmaf(xs4[i], wf[j], acc2[i][j]);
    }

    // ---- store u_raw / z as bf16
    {
        unsigned short* dst = (c0 < 128) ? u_raw : z_out;
        const int cc0 = c0 & 127;
        #pragma unroll
        for (int i = 0; i < 4; ++i) {
            const int bgl = m0 + mq*4 + i;
            unsigned short* p = dst + ((size_t)bgl * TL + l) * TDI + cc0;
            unsigned int pk[8];
            #pragma unroll
            for (int q = 0; q < 8; ++q)
                pk[q] = (unsigned int)f2bf(acc2[i][2*q]) |
                        ((unsigned int)f2bf(acc2[i][2*q+1]) << 16);
            *(uint4*)(p)     = make_uint4(pk[0], pk[1], pk[2], pk[3]);
            *(uint4*)(p + 8) = make_uint4(pk[4], pk[5], pk[6], pk[7]);
        }
    }
}

// =====================================================================
// KB: per-batch fused conv+silu -> xproj -> dtproj+softplus -> scan ->
//     gate -> out proj
// =====================================================================
__global__ __launch_bounds__(256, 2)
void kb_mamba(const unsigned short* __restrict__ u_raw,
              const unsigned short* __restrict__ z_in,
              const float* __restrict__ conv_w,
              const float* __restrict__ conv_b,
              const float* __restrict__ xproj_w,
              const float* __restrict__ dtproj_w,
              const float* __restrict__ dtproj_b,
              const float* __restrict__ A_log,
              const float* __restrict__ Dvec,
              const float* __restrict__ out_w,
              float* __restrict__ out)
{
    __shared__ float u[TL * 132];     // u (post conv+silu) -> y -> gated, stride 132
    __shared__ float dbc[TL * 36];    // [t][0:4)=dt [4:20)=B [20:36)=C
    __shared__ float xw[128 * 36];    // xproj_w^T [k][j]; later overlaid by owl bf16

    const int tid = threadIdx.x;
    const int b   = blockIdx.x;

    // ---- stage xproj_w -> xw[k][j]
    for (int idx = tid; idx < 36*128; idx += 256) {
        const int j = idx >> 7, k = idx & 127;   // xproj_w[j][k]
        xw[k*36 + j] = xproj_w[idx];
    }

    // ---- causal depthwise conv + SiLU -> u
    {
        const int c = tid & 127, half = tid >> 7;
        const int t0 = half ? 39 : 0, t1 = half ? TL : 39;
        const float w0 = conv_w[c*4+0], w1 = conv_w[c*4+1];
        const float w2 = conv_w[c*4+2], w3 = conv_w[c*4+3];
        const float cb = conv_b[c];
        const unsigned short* up = u_raw + (size_t)b * TL * TDI + c;
        float h3 = 0.f, h2 = 0.f, h1 = 0.f;
        if (half) {
            h3 = bf2f(up[(t0-3)*TDI]);
            h2 = bf2f(up[(t0-2)*TDI]);
            h1 = bf2f(up[(t0-1)*TDI]);
        }
        for (int t = t0; t < t1; ++t) {
            const float r = bf2f(up[t*TDI]);
            const float v = fmaf(w3, r, fmaf(w2, h1, fmaf(w1, h2, fmaf(w0, h3, cb))));
            u[t*132 + c] = v * fsig(v);
            h3 = h2; h2 = h1; h1 = r;
        }
    }
    __syncthreads();

    // ---- xproj: dbc[t][j] = sum_k u[t][k] * xproj_w[j][k]
    if (tid < 180) {
        const int tt = tid / 9, tj = tid % 9;
        const int t0 = tt * 4, j0 = tj * 4;
        float acc[4][4];
        #pragma unroll
        for (int i = 0; i < 4; ++i)
            #pragma unroll
            for (int j = 0; j < 4; ++j) acc[i][j] = 0.f;

        for (int kk = 0; kk < 32; ++kk) {
            const int k = kk * 4;
            const float4 wv0 = *(const float4*)&xw[(k+0)*36 + j0];
            const float4 wv1 = *(const float4*)&xw[(k+1)*36 + j0];
            const float4 wv2 = *(const float4*)&xw[(k+2)*36 + j0];
            const float4 wv3 = *(const float4*)&xw[(k+3)*36 + j0];
            const float wr[4][4] = {{wv0.x,wv0.y,wv0.z,wv0.w},
                                    {wv1.x,wv1.y,wv1.z,wv1.w},
                                    {wv2.x,wv2.y,wv2.z,wv2.w},
                                    {wv3.x,wv3.y,wv3.z,wv3.w}};
            #pragma unroll
            for (int i = 0; i < 4; ++i) {
                const int ti = (t0 + i < 77) ? (t0 + i) : 76;
                const float4 uv = *(const float4*)&u[ti*132 + k];
                const float us[4] = {uv.x, uv.y, uv.z, uv.w};
                #pragma unroll
                for (int r = 0; r < 4; ++r)
                    #pragma unroll
                    for (int j = 0; j < 4; ++j)
                        acc[i][j] = fmaf(us[r], wr[r][j], acc[i][j]);
            }
        }
        #pragma unroll
        for (int i = 0; i < 4; ++i) {
            const int t = t0 + i;
            if (t < 77)
                *(float4*)&dbc[t*36 + j0] =
                    make_float4(acc[i][0], acc[i][1], acc[i][2], acc[i][3]);
        }
    }
    __syncthreads();

    // ---- selective scan (thread pair per channel; 8 states each; no barriers)
    {
        const int d  = tid >> 1;
        const int sh = tid & 1;
        const int sb = sh * 8;
        float Av[8];
        #pragma unroll
        for (int i = 0; i < 8; ++i) Av[i] = -__expf(A_log[d*16 + sb + i]);
        const float4 dtw = *(const float4*)&dtproj_w[d*4];
        const float dtb = dtproj_b[d];
        const float Dd  = Dvec[d];
        float h[8];
        #pragma unroll
        for (int i = 0; i < 8; ++i) h[i] = 0.f;

        for (int t = 0; t < TL; ++t) {
            const float4 dtv = *(const float4*)&dbc[t*36];
            float pre = fmaf(dtv.x, dtw.x, fmaf(dtv.y, dtw.y,
                         fmaf(dtv.z, dtw.z, fmaf(dtv.w, dtw.w, dtb))));
            float dl = __logf(1.0f + __expf(pre));      // softplus
            if (pre > 20.0f) dl = pre;
            const float ut = u[t*132 + d];
            const float du = dl * ut;
            const float4 Bv0 = *(const float4*)&dbc[t*36 + 4  + sb];
            const float4 Bv1 = *(const float4*)&dbc[t*36 + 8  + sb];
            const float4 Cv0 = *(const float4*)&dbc[t*36 + 20 + sb];
            const float4 Cv1 = *(const float4*)&dbc[t*36 + 24 + sb];
            const float Bs[8] = {Bv0.x,Bv0.y,Bv0.z,Bv0.w, Bv1.x,Bv1.y,Bv1.z,Bv1.w};
            const float Cs[8] = {Cv0.x,Cv0.y,Cv0.z,Cv0.w, Cv1.x,Cv1.y,Cv1.z,Cv1.w};
            float ys = 0.f;
            #pragma unroll
            for (int i = 0; i < 8; ++i) {
                const float dA = __expf(dl * Av[i]);
                h[i] = fmaf(h[i], dA, du * Bs[i]);
                ys = fmaf(h[i], Cs[i], ys);
            }
            ys += __shfl_xor(ys, 1, 64);
            if (!sh) u[t*132 + d] = fmaf(Dd, ut, ys);   // y + D*u (column-exclusive)
        }
    }
    __syncthreads();

    // ---- stage out_w bf16 (over dead xw) + gate y *= silu(z)
    unsigned short* owl = (unsigned short*)xw;   // [128][68]
    for (int idx = tid; idx < 64*128; idx += 256) {
        const int w = idx >> 7, dd = idx & 127;  // out_w[w][dd]
        owl[dd*68 + w] = f2bf(out_w[idx]);
    }
    for (int idx = tid; idx < TL*TDI; idx += 256) {
        const int t = idx >> 7, c = idx & 127;
        const float zv = bf2f(z_in[(size_t)b * TL * TDI + idx]);
        u[t*132 + c] = u[t*132 + c] * (zv * fsig(zv));
    }
    __syncthreads();

    // ---- out projection: out[t][w] = sum_d g[t][d] * out_w[w][d]
    {
        const int tq = tid >> 4;       // 0..15 -> t0 = tq*5
        const int wq = tid & 15;       // w0 = wq*4
        const int t0 = tq * 5, w0 = wq * 4;
        float acc[5][4];
        #pragma unroll
        for (int i = 0; i < 5; ++i)
            #pragma unroll
            for (int j = 0; j < 4; ++j) acc[i][j] = 0.f;

        for (int d4 = 0; d4 < 32; ++d4) {
            const int dd = d4 * 4;
            float of[4][4];
            #pragma unroll
            for (int dj = 0; dj < 4; ++dj) {
                const uint2 o2 = *(const uint2*)&owl[(dd+dj)*68 + w0];
                of[dj][0] = bflo(o2.x); of[dj][1] = bfhi(o2.x);
                of[dj][2] = bflo(o2.y); of[dj][3] = bfhi(o2.y);
            }
            #pragma unroll
            for (int i = 0; i < 5; ++i) {
                const int ti = (t0 + i < 77) ? (t0 + i) : 76;
                const float4 gv = *(const float4*)&u[ti*132 + dd];
                const float gs[4] = {gv.x, gv.y, gv.z, gv.w};
                #pragma unroll
                for (int dj = 0; dj < 4; ++dj)
                    #pragma unroll
                    for (int j = 0; j < 4; ++j)
                        acc[i][j] = fmaf(gs[dj], of[dj][j], acc[i][j]);
            }
        }
        float* op = out + (size_t)b * TL * TW;
        #pragma unroll
        for (int i = 0; i < 5; ++i) {
            const int t = t0 + i;
            if (t < 77)
                *(float4*)&op[t*64 + w0] =
                    make_float4(acc[i][0], acc[i][1], acc[i][2], acc[i][3]);
        }
    }
}

// =====================================================================
extern "C" void kernel_launch(void* const* d_in, const int* in_sizes, int n_in,
                              void* d_out, int out_size, void* d_ws, size_t ws_size,
                              hipStream_t stream)
{
    const float* enc      = (const float*)d_in[0];
    const float* dec_w    = (const float*)d_in[1];
    const float* dec_b    = (const float*)d_in[2];
    const float* in_w     = (const float*)d_in[3];
    const float* conv_w   = (const float*)d_in[4];
    const float* conv_b   = (const float*)d_in[5];
    const float* xproj_w  = (const float*)d_in[6];
    const float* dtproj_w = (const float*)d_in[7];
    const float* dtproj_b = (const float*)d_in[8];
    const float* A_log    = (const float*)d_in[9];
    const float* Dvec     = (const float*)d_in[10];
    const float* out_w    = (const float*)d_in[11];
    float* out = (float*)d_out;

    // workspace: u_raw + z as bf16, 2 * 2048*77*128*2 B = 80.7 MB
    unsigned short* u_raw = (unsigned short*)d_ws;
    unsigned short* z_buf = u_raw + (size_t)TB * TL * TDI;

    dim3 gA(TB / 64, TL);
    ka_dec_inproj<<<gA, dim3(256), 0, stream>>>(enc, dec_w, dec_b, in_w, u_raw, z_buf);
    kb_mamba<<<dim3(TB), dim3(256), 0, stream>>>(u_raw, z_buf, conv_w, conv_b,
                                                 xproj_w, dtproj_w, dtproj_b,
                                                 A_log, Dvec, out_w, out);
}

// Round 5
// 256.658 us; speedup vs baseline: 1.7809x; 1.7809x over previous
//
#include <hip/hip_runtime.h>
#include <cstdint>
#include <cstddef>

#define TB 2048
#define TL 77
#define TDI 128

typedef __bf16 bf16x8 __attribute__((ext_vector_type(8)));
typedef float f32x4 __attribute__((ext_vector_type(4)));

// ---------- helpers ----------
__device__ __forceinline__ float bf2f(unsigned short h) {
    unsigned int u = ((unsigned int)h) << 16;
    float f; __builtin_memcpy(&f, &u, 4); return f;
}
__device__ __forceinline__ unsigned short f2bf(float f) {
    unsigned int u; __builtin_memcpy(&u, &f, 4);
    u = (u + 0x7fffu + ((u >> 16) & 1u)) >> 16;
    return (unsigned short)u;
}
__device__ __forceinline__ float fsig(float x) {
    return __builtin_amdgcn_rcpf(1.0f + __expf(-x));
}
__device__ __forceinline__ uint4 pack8(float4 a, float4 b) {
    uint4 r;
    r.x = (unsigned int)f2bf(a.x) | ((unsigned int)f2bf(a.y) << 16);
    r.y = (unsigned int)f2bf(a.z) | ((unsigned int)f2bf(a.w) << 16);
    r.z = (unsigned int)f2bf(b.x) | ((unsigned int)f2bf(b.y) << 16);
    r.w = (unsigned int)f2bf(b.z) | ((unsigned int)f2bf(b.w) << 16);
    return r;
}

// =====================================================================
// KA: x = enc @ dec_w.T + dec_b  ->  xz = x @ in_w.T  (all bf16 MFMA)
// block = (64 batches, one l), 256 threads = 4 waves (wave = m-tile)
// LDS k-chunked layout [K/8][rows][8] bf16, 16B chunk granularity.
// =====================================================================
#define KA_ENC 0            // [16 kc][65 pad][8]  stride 1040  (16640 B)
#define KA_DEC 16640        // [16 kc][65 pad][8]  stride 1040  (16640 B)
#define KA_TRS 0            // transpose buf [64 m][528 B]       (33792 B)
#define KA_R2  33792        // x  [8 kc][65 pad][8] stride 1040  (8320 B)
#define KA_R3  42112        // in_w [8 kc][257 pad][8] stride 4112 (32896 B)
#define KA_LDS 75008

__global__ __launch_bounds__(256, 2)
void ka_dec_inproj(const float* __restrict__ enc,
                   const float* __restrict__ dec_w,
                   const float* __restrict__ dec_b,
                   const float* __restrict__ in_w,
                   unsigned short* __restrict__ u_raw,
                   unsigned short* __restrict__ z_out)
{
    __shared__ __align__(16) char sm[KA_LDS];

    const int tid = threadIdx.x;
    const int m0  = blockIdx.x * 64;
    const int l   = blockIdx.y;
    const int wv  = tid >> 6;         // wave = m-tile
    const int ln  = tid & 63;
    const int lr  = ln & 15;
    const int lg  = ln >> 4;

    // ---- P0: stage encA, decB (bf16, k-chunked)
    for (int idx = tid; idx < 1024; idx += 256) {
        const int m = idx >> 4, kc = idx & 15;
        const float* p = enc + (size_t)(m0 + m) * 128 + kc * 8;
        *(uint4*)(sm + KA_ENC + kc*1040 + m*16) =
            pack8(*(const float4*)p, *(const float4*)(p + 4));
        const float* q = dec_w + (size_t)(l*64 + m) * 128 + kc * 8;
        *(uint4*)(sm + KA_DEC + kc*1040 + m*16) =
            pack8(*(const float4*)q, *(const float4*)(q + 4));
    }
    // ---- stage in_w [8 kc][256 c][8]
    for (int idx = tid; idx < 2048; idx += 256) {
        const int c = idx >> 3, kc = idx & 7;
        const float* p = in_w + (size_t)c * 64 + kc * 8;
        *(uint4*)(sm + KA_R3 + kc*4112 + c*16) =
            pack8(*(const float4*)p, *(const float4*)(p + 4));
    }
    __syncthreads();

    // ---- P1: GEMM1  x[m][w], M=64 N=64 K=128
    f32x4 acc1[4];
    #pragma unroll
    for (int nt = 0; nt < 4; ++nt) acc1[nt] = (f32x4){0.f, 0.f, 0.f, 0.f};
    #pragma unroll
    for (int ks = 0; ks < 4; ++ks) {
        const bf16x8 a = *(const bf16x8*)(sm + KA_ENC + (ks*4+lg)*1040 + (wv*16+lr)*16);
        #pragma unroll
        for (int nt = 0; nt < 4; ++nt) {
            const bf16x8 bb = *(const bf16x8*)(sm + KA_DEC + (ks*4+lg)*1040 + (nt*16+lr)*16);
            acc1[nt] = __builtin_amdgcn_mfma_f32_16x16x32_bf16(a, bb, acc1[nt], 0, 0, 0);
        }
    }

    // ---- P2: x (+bias) -> R2 k-chunked bf16 (wave-local rows)
    #pragma unroll
    for (int nt = 0; nt < 4; ++nt) {
        const int w = nt*16 + lr;
        const float bias = dec_b[l*64 + w];
        #pragma unroll
        for (int r = 0; r < 4; ++r) {
            const int m = wv*16 + lg*4 + r;
            *(unsigned short*)(sm + KA_R2 + (w>>3)*1040 + m*16 + (w&7)*2) =
                f2bf(acc1[nt][r] + bias);
        }
    }

    // ---- P3: in_proj  xz[m][c], M=64 N=256 K=64
    f32x4 acc2[16];
    #pragma unroll
    for (int nt = 0; nt < 16; ++nt) acc2[nt] = (f32x4){0.f, 0.f, 0.f, 0.f};
    #pragma unroll
    for (int ks = 0; ks < 2; ++ks) {
        const bf16x8 a = *(const bf16x8*)(sm + KA_R2 + (ks*4+lg)*1040 + (wv*16+lr)*16);
        #pragma unroll
        for (int nt = 0; nt < 16; ++nt) {
            const bf16x8 bb = *(const bf16x8*)(sm + KA_R3 + (ks*4+lg)*4112 + (nt*16+lr)*16);
            acc2[nt] = __builtin_amdgcn_mfma_f32_16x16x32_bf16(a, bb, acc2[nt], 0, 0, 0);
        }
    }
    __syncthreads();   // all waves done reading KA_ENC/KA_DEC (reused below)

    // ---- P4: xz -> transpose buffer [m][256 c] bf16, stride 528 B
    #pragma unroll
    for (int nt = 0; nt < 16; ++nt) {
        const int c = nt*16 + lr;
        #pragma unroll
        for (int r = 0; r < 4; ++r) {
            const int m = wv*16 + lg*4 + r;
            *(unsigned short*)(sm + KA_TRS + m*528 + c*2) = f2bf(acc2[nt][r]);
        }
    }
    __syncthreads();

    // ---- P5: coalesced global store (uint4 = 8 bf16)
    for (int idx = tid; idx < 2048; idx += 256) {
        const int m = idx >> 5, ch = idx & 31;
        const uint4 v = *(const uint4*)(sm + KA_TRS + m*528 + ch*16);
        const size_t base = ((size_t)(m0 + m) * TL + l) * TDI;
        if (ch < 16) *(uint4*)(u_raw + base + ch*8) = v;
        else         *(uint4*)(z_out + base + (ch-16)*8) = v;
    }
}

// =====================================================================
// KB: per-batch fused conv+silu -> xproj(MFMA) -> scan -> gate ->
//     outproj(MFMA).  u/y bf16 k-chunked in LDS.
// =====================================================================
#define KB_U   0            // u/y [16 kc][81 pad][8] stride 1296  (20736 B)
#define KB_DBC 20736        // dbc [80 t][40 pad] f32              (12800 B)
#define KB_WB  33536        // xw [16][49][8] s784 | out_w [16][65][8] s1040 (16640 B)
#define KB_LDS 50176

__global__ __launch_bounds__(256, 3)
void kb_mamba(const unsigned short* __restrict__ u_raw,
              const unsigned short* __restrict__ z_in,
              const float* __restrict__ conv_w,
              const float* __restrict__ conv_b,
              const float* __restrict__ xproj_w,
              const float* __restrict__ dtproj_w,
              const float* __restrict__ dtproj_b,
              const float* __restrict__ A_log,
              const float* __restrict__ Dvec,
              const float* __restrict__ out_w,
              float* __restrict__ out)
{
    __shared__ __align__(16) char sm[KB_LDS];
    float* dbc = (float*)(sm + KB_DBC);

    const int tid = threadIdx.x;
    const int b   = blockIdx.x;
    const int wv  = tid >> 6;
    const int ln  = tid & 63;
    const int lr  = ln & 15;
    const int lg  = ln >> 4;

    // ---- P0: stage xproj_w -> WB [16 kc][48 n][8] bf16 (zero-pad n>=36)
    for (int idx = tid; idx < 768; idx += 256) {
        const int n = idx >> 4, kc = idx & 15;
        uint4 v = make_uint4(0u, 0u, 0u, 0u);
        if (n < 36) {
            const float* p = xproj_w + (size_t)n * 128 + kc * 8;
            v = pack8(*(const float4*)p, *(const float4*)(p + 4));
        }
        *(uint4*)(sm + KB_WB + kc*784 + n*16) = v;
    }

    // ---- P1: causal conv (4-tap FIR, fully parallel over (t, c8)) + SiLU
    for (int idx = tid; idx < 1280; idx += 256) {
        const int t = idx >> 4, c8 = idx & 15;
        uint4 r = make_uint4(0u, 0u, 0u, 0u);
        if (t < 77) {
            const unsigned short* base = u_raw + (size_t)b * TL * TDI + c8 * 8;
            uint4 rows[4];
            #pragma unroll
            for (int j = 0; j < 4; ++j) {
                const int tt = t - 3 + j;
                rows[j] = (tt >= 0) ? *(const uint4*)(base + (size_t)tt * TDI)
                                    : make_uint4(0u, 0u, 0u, 0u);
            }
            #pragma unroll
            for (int e = 0; e < 8; ++e) {
                const int c = c8*8 + e;
                const float4 cw = *(const float4*)(conv_w + c*4);
                const float x0 = bf2f(((const unsigned short*)&rows[0])[e]);
                const float x1 = bf2f(((const unsigned short*)&rows[1])[e]);
                const float x2 = bf2f(((const unsigned short*)&rows[2])[e]);
                const float x3 = bf2f(((const unsigned short*)&rows[3])[e]);
                float v = fmaf(cw.x, x0, fmaf(cw.y, x1,
                          fmaf(cw.z, x2, fmaf(cw.w, x3, conv_b[c]))));
                v = v * fsig(v);
                ((unsigned short*)&r)[e] = f2bf(v);
            }
        }
        *(uint4*)(sm + KB_U + c8*1296 + t*16) = r;   // rows 77..79 zeroed
    }
    __syncthreads();

    // ---- P2: xproj MFMA  dbc[t][n], M=80 N=48 K=128 (15 tiles / 4 waves)
    for (int tile = wv; tile < 15; tile += 4) {
        const int mt = tile / 3, nt = tile % 3;
        f32x4 acc = (f32x4){0.f, 0.f, 0.f, 0.f};
        #pragma unroll
        for (int ks = 0; ks < 4; ++ks) {
            const bf16x8 a = *(const bf16x8*)(sm + KB_U  + (ks*4+lg)*1296 + (mt*16+lr)*16);
            const bf16x8 bb = *(const bf16x8*)(sm + KB_WB + (ks*4+lg)*784  + (nt*16+lr)*16);
            acc = __builtin_amdgcn_mfma_f32_16x16x32_bf16(a, bb, acc, 0, 0, 0);
        }
        const int n = nt*16 + lr;
        if (n < 36) {
            #pragma unroll
            for (int r = 0; r < 4; ++r)
                dbc[(mt*16 + lg*4 + r)*40 + n] = acc[r];
        }
    }
    __syncthreads();

    // ---- P3: selective scan (thread pair per channel; y overwrites u)
    {
        const int d  = tid >> 1;
        const int sh = tid & 1;
        const int sb = sh * 8;
        float Av[8];
        #pragma unroll
        for (int i = 0; i < 8; ++i) Av[i] = -__expf(A_log[d*16 + sb + i]);
        const float4 dtw = *(const float4*)(dtproj_w + d*4);
        const float dtb = dtproj_b[d];
        const float Dd  = Dvec[d];
        char* uptr = sm + KB_U + (d>>3)*1296 + (d&7)*2;
        float h[8];
        #pragma unroll
        for (int i = 0; i < 8; ++i) h[i] = 0.f;

        for (int t = 0; t < TL; ++t) {
            const float4 dtv = *(const float4*)&dbc[t*40];
            const float pre = fmaf(dtv.x, dtw.x, fmaf(dtv.y, dtw.y,
                              fmaf(dtv.z, dtw.z, fmaf(dtv.w, dtw.w, dtb))));
            float dl = __logf(1.0f + __expf(pre));
            if (pre > 20.0f) dl = pre;
            const float ut = bf2f(*(unsigned short*)(uptr + t*16));
            const float du = dl * ut;
            const float4 Bv0 = *(const float4*)&dbc[t*40 + 4  + sb];
            const float4 Bv1 = *(const float4*)&dbc[t*40 + 8  + sb];
            const float4 Cv0 = *(const float4*)&dbc[t*40 + 20 + sb];
            const float4 Cv1 = *(const float4*)&dbc[t*40 + 24 + sb];
            const float Bs[8] = {Bv0.x,Bv0.y,Bv0.z,Bv0.w, Bv1.x,Bv1.y,Bv1.z,Bv1.w};
            const float Cs[8] = {Cv0.x,Cv0.y,Cv0.z,Cv0.w, Cv1.x,Cv1.y,Cv1.z,Cv1.w};
            float ys = 0.f;
            #pragma unroll
            for (int i = 0; i < 8; ++i) {
                const float dA = __expf(dl * Av[i]);
                h[i] = fmaf(h[i], dA, du * Bs[i]);
                ys = fmaf(h[i], Cs[i], ys);
            }
            ys += __shfl_xor(ys, 1, 64);
            if (!sh)
                *(unsigned short*)(uptr + t*16) = f2bf(fmaf(Dd, ut, ys));
        }
    }
    __syncthreads();

    // ---- P4: stage out_w (over dead xw) + gate y *= silu(z)
    for (int idx = tid; idx < 1024; idx += 256) {
        const int n = idx >> 4, kc = idx & 15;
        const float* p = out_w + (size_t)n * 128 + kc * 8;
        *(uint4*)(sm + KB_WB + kc*1040 + n*16) =
            pack8(*(const float4*)p, *(const float4*)(p + 4));
    }
    for (int idx = tid; idx < 1232; idx += 256) {     // 77*16 (t, d8)
        const int t = idx >> 4, d8 = idx & 15;
        const uint4 zv = *(const uint4*)(z_in + ((size_t)b * TL + t) * TDI + d8*8);
        uint4 uv = *(uint4*)(sm + KB_U + d8*1296 + t*16);
        #pragma unroll
        for (int e = 0; e < 8; ++e) {
            const float z = bf2f(((const unsigned short*)&zv)[e]);
            const float y = bf2f(((const unsigned short*)&uv)[e]);
            ((unsigned short*)&uv)[e] = f2bf(y * (z * fsig(z)));
        }
        *(uint4*)(sm + KB_U + d8*1296 + t*16) = uv;
    }
    __syncthreads();

    // ---- P5: outproj MFMA  out[t][w], M=80 N=64 K=128 (20 tiles / 4 waves)
    for (int tile = wv; tile < 20; tile += 4) {
        const int mt = tile >> 2, nt = tile & 3;
        f32x4 acc = (f32x4){0.f, 0.f, 0.f, 0.f};
        #pragma unroll
        for (int ks = 0; ks < 4; ++ks) {
            const bf16x8 a = *(const bf16x8*)(sm + KB_U  + (ks*4+lg)*1296 + (mt*16+lr)*16);
            const bf16x8 bb = *(const bf16x8*)(sm + KB_WB + (ks*4+lg)*1040 + (nt*16+lr)*16);
            acc = __builtin_amdgcn_mfma_f32_16x16x32_bf16(a, bb, acc, 0, 0, 0);
        }
        #pragma unroll
        for (int r = 0; r < 4; ++r) {
            const int t = mt*16 + lg*4 + r;
            if (t < 77)
                out[((size_t)b * TL + t) * 64 + nt*16 + lr] = acc[r];
        }
    }
}

// =====================================================================
extern "C" void kernel_launch(void* const* d_in, const int* in_sizes, int n_in,
                              void* d_out, int out_size, void* d_ws, size_t ws_size,
                              hipStream_t stream)
{
    const float* enc      = (const float*)d_in[0];
    const float* dec_w    = (const float*)d_in[1];
    const float* dec_b    = (const float*)d_in[2];
    const float* in_w     = (const float*)d_in[3];
    const float* conv_w   = (const float*)d_in[4];
    const float* conv_b   = (const float*)d_in[5];
    const float* xproj_w  = (const float*)d_in[6];
    const float* dtproj_w = (const float*)d_in[7];
    const float* dtproj_b = (const float*)d_in[8];
    const float* A_log    = (const float*)d_in[9];
    const float* Dvec     = (const float*)d_in[10];
    const float* out_w    = (const float*)d_in[11];
    float* out = (float*)d_out;

    unsigned short* u_raw = (unsigned short*)d_ws;
    unsigned short* z_buf = u_raw + (size_t)TB * TL * TDI;

    dim3 gA(TB / 64, TL);
    ka_dec_inproj<<<gA, dim3(256), 0, stream>>>(enc, dec_w, dec_b, in_w, u_raw, z_buf);
    kb_mamba<<<dim3(TB), dim3(256), 0, stream>>>(u_raw, z_buf, conv_w, conv_b,
                                                 xproj_w, dtproj_w, dtproj_b,
                                                 A_log, Dvec, out_w, out);
}

// Round 6
// 251.521 us; speedup vs baseline: 1.8172x; 1.0204x over previous
//
#include <hip/hip_runtime.h>
#include <cstdint>
#include <cstddef>

#define TB 2048
#define TL 77
#define TDI 128

typedef __bf16 bf16x8 __attribute__((ext_vector_type(8)));
typedef float f32x4 __attribute__((ext_vector_type(4)));

// ---------- helpers ----------
__device__ __forceinline__ float bf2f(unsigned short h) {
    unsigned int u = ((unsigned int)h) << 16;
    float f; __builtin_memcpy(&f, &u, 4); return f;
}
__device__ __forceinline__ unsigned short f2bf(float f) {
    unsigned int u; __builtin_memcpy(&u, &f, 4);
    u = (u + 0x7fffu + ((u >> 16) & 1u)) >> 16;
    return (unsigned short)u;
}
__device__ __forceinline__ float fsig(float x) {
    return __builtin_amdgcn_rcpf(1.0f + __expf(-x));
}
__device__ __forceinline__ uint4 pack8(float4 a, float4 b) {
    uint4 r;
    r.x = (unsigned int)f2bf(a.x) | ((unsigned int)f2bf(a.y) << 16);
    r.y = (unsigned int)f2bf(a.z) | ((unsigned int)f2bf(a.w) << 16);
    r.z = (unsigned int)f2bf(b.x) | ((unsigned int)f2bf(b.y) << 16);
    r.w = (unsigned int)f2bf(b.z) | ((unsigned int)f2bf(b.w) << 16);
    return r;
}

// =====================================================================
// KW: one-shot f32 -> bf16 conversion of enc / dec_w / in_w /
//     xproj_w (zero-padded to 48 rows) / out_w into workspace.
//     Row-major bf16, so consumers load 16B chunks lane-linearly.
// chunk counts: enc 32768 | dec 78848 | inw 2048 | xpw 768 | ow 1024
// total 115456 = 451 * 256 exactly.
// =====================================================================
__global__ __launch_bounds__(256)
void kw_convert(const float* __restrict__ enc, const float* __restrict__ dec_w,
                const float* __restrict__ in_w, const float* __restrict__ xproj_w,
                const float* __restrict__ out_w,
                unsigned short* __restrict__ enc_bf, unsigned short* __restrict__ dec_bf,
                unsigned short* __restrict__ inw_bf, unsigned short* __restrict__ xpw_bf,
                unsigned short* __restrict__ ow_bf)
{
    int rel = blockIdx.x * 256 + threadIdx.x;
    const float* src = nullptr;
    unsigned short* dst;
    if (rel < 32768) { src = enc + (size_t)rel * 8; dst = enc_bf + (size_t)rel * 8; }
    else if ((rel -= 32768) < 78848) { src = dec_w + (size_t)rel * 8; dst = dec_bf + (size_t)rel * 8; }
    else if ((rel -= 78848) < 2048)  { src = in_w  + (size_t)rel * 8; dst = inw_bf + (size_t)rel * 8; }
    else if ((rel -= 2048)  < 768) {
        dst = xpw_bf + (size_t)rel * 8;
        if ((rel >> 4) < 36) src = xproj_w + (size_t)rel * 8;   // rows 36..47 stay zero
    }
    else { rel -= 768; src = out_w + (size_t)rel * 8; dst = ow_bf + (size_t)rel * 8; }
    uint4 v = make_uint4(0u, 0u, 0u, 0u);
    if (src) v = pack8(*(const float4*)src, *(const float4*)(src + 4));
    *(uint4*)dst = v;
}

// =====================================================================
// KA: x = enc @ dec_w.T + dec_b  ->  xz = x @ in_w.T  (all bf16 MFMA)
// block = (64 batches, one l), 256 threads = 4 waves (wave = m-tile)
// Staging is now pure 16B copies from pre-converted bf16 (no f2bf).
// =====================================================================
#define KA_ENC 0            // [16 kc][65 pad][8]  stride 1040  (16640 B)
#define KA_DEC 16640        // [16 kc][65 pad][8]  stride 1040  (16640 B)
#define KA_TRS 0            // transpose buf [64 m][528 B]       (33792 B)
#define KA_R2  33792        // x  [8 kc][65 pad][8] stride 1040  (8320 B)
#define KA_R3  42112        // in_w [8 kc][257 pad][8] stride 4112 (32896 B)
#define KA_LDS 75008

__global__ __launch_bounds__(256, 2)
void ka_dec_inproj(const unsigned short* __restrict__ enc_bf,
                   const unsigned short* __restrict__ dec_bf,
                   const float* __restrict__ dec_b,
                   const unsigned short* __restrict__ inw_bf,
                   unsigned short* __restrict__ u_raw,
                   unsigned short* __restrict__ z_out)
{
    __shared__ __align__(16) char sm[KA_LDS];

    const int tid = threadIdx.x;
    const int m0  = blockIdx.x * 64;
    const int l   = blockIdx.y;
    const int wv  = tid >> 6;         // wave = m-tile
    const int ln  = tid & 63;
    const int lr  = ln & 15;
    const int lg  = ln >> 4;

    // ---- P0: stage enc tile, dec_w tile, in_w (straight 16B copies)
    {
        const unsigned short* ebase = enc_bf + (size_t)m0 * 128;
        const unsigned short* dbase = dec_bf + (size_t)l * 64 * 128;
        for (int idx = tid; idx < 1024; idx += 256) {
            const int m = idx >> 4, kc = idx & 15;   // elem off = idx*8
            *(uint4*)(sm + KA_ENC + kc*1040 + m*16) = *(const uint4*)(ebase + idx*8);
            *(uint4*)(sm + KA_DEC + kc*1040 + m*16) = *(const uint4*)(dbase + idx*8);
        }
        for (int idx = tid; idx < 2048; idx += 256) {
            const int c = idx >> 3, kc = idx & 7;    // elem off = idx*8
            *(uint4*)(sm + KA_R3 + kc*4112 + c*16) = *(const uint4*)(inw_bf + idx*8);
        }
    }
    __syncthreads();

    // ---- P1: GEMM1  x[m][w], M=64 N=64 K=128
    f32x4 acc1[4];
    #pragma unroll
    for (int nt = 0; nt < 4; ++nt) acc1[nt] = (f32x4){0.f, 0.f, 0.f, 0.f};
    #pragma unroll
    for (int ks = 0; ks < 4; ++ks) {
        const bf16x8 a = *(const bf16x8*)(sm + KA_ENC + (ks*4+lg)*1040 + (wv*16+lr)*16);
        #pragma unroll
        for (int nt = 0; nt < 4; ++nt) {
            const bf16x8 bb = *(const bf16x8*)(sm + KA_DEC + (ks*4+lg)*1040 + (nt*16+lr)*16);
            acc1[nt] = __builtin_amdgcn_mfma_f32_16x16x32_bf16(a, bb, acc1[nt], 0, 0, 0);
        }
    }

    // ---- P2: x (+bias) -> R2 k-chunked bf16 (wave-local rows)
    #pragma unroll
    for (int nt = 0; nt < 4; ++nt) {
        const int w = nt*16 + lr;
        const float bias = dec_b[l*64 + w];
        #pragma unroll
        for (int r = 0; r < 4; ++r) {
            const int m = wv*16 + lg*4 + r;
            *(unsigned short*)(sm + KA_R2 + (w>>3)*1040 + m*16 + (w&7)*2) =
                f2bf(acc1[nt][r] + bias);
        }
    }

    // ---- P3: in_proj  xz[m][c], M=64 N=256 K=64
    f32x4 acc2[16];
    #pragma unroll
    for (int nt = 0; nt < 16; ++nt) acc2[nt] = (f32x4){0.f, 0.f, 0.f, 0.f};
    #pragma unroll
    for (int ks = 0; ks < 2; ++ks) {
        const bf16x8 a = *(const bf16x8*)(sm + KA_R2 + (ks*4+lg)*1040 + (wv*16+lr)*16);
        #pragma unroll
        for (int nt = 0; nt < 16; ++nt) {
            const bf16x8 bb = *(const bf16x8*)(sm + KA_R3 + (ks*4+lg)*4112 + (nt*16+lr)*16);
            acc2[nt] = __builtin_amdgcn_mfma_f32_16x16x32_bf16(a, bb, acc2[nt], 0, 0, 0);
        }
    }
    __syncthreads();   // all waves done reading KA_ENC/KA_DEC (reused below)

    // ---- P4: xz -> transpose buffer [m][256 c] bf16, stride 528 B
    #pragma unroll
    for (int nt = 0; nt < 16; ++nt) {
        const int c = nt*16 + lr;
        #pragma unroll
        for (int r = 0; r < 4; ++r) {
            const int m = wv*16 + lg*4 + r;
            *(unsigned short*)(sm + KA_TRS + m*528 + c*2) = f2bf(acc2[nt][r]);
        }
    }
    __syncthreads();

    // ---- P5: coalesced global store (uint4 = 8 bf16)
    for (int idx = tid; idx < 2048; idx += 256) {
        const int m = idx >> 5, ch = idx & 31;
        const uint4 v = *(const uint4*)(sm + KA_TRS + m*528 + ch*16);
        const size_t base = ((size_t)(m0 + m) * TL + l) * TDI;
        if (ch < 16) *(uint4*)(u_raw + base + ch*8) = v;
        else         *(uint4*)(z_out + base + (ch-16)*8) = v;
    }
}

// =====================================================================
// KB: per-batch fused conv+silu -> xproj(MFMA) -> scan -> gate ->
//     outproj(MFMA).  u/y bf16 k-chunked in LDS.
// =====================================================================
#define KB_U   0            // u/y [16 kc][81 pad][8] stride 1296  (20736 B)
#define KB_DBC 20736        // dbc [80 t][40 pad] f32              (12800 B)
#define KB_WB  33536        // xw [16][49][8] s784 | out_w [16][65][8] s1040 (16640 B)
#define KB_LDS 50176

__global__ __launch_bounds__(256, 3)
void kb_mamba(const unsigned short* __restrict__ u_raw,
              const unsigned short* __restrict__ z_in,
              const float* __restrict__ conv_w,
              const float* __restrict__ conv_b,
              const unsigned short* __restrict__ xpw_bf,
              const float* __restrict__ dtproj_w,
              const float* __restrict__ dtproj_b,
              const float* __restrict__ A_log,
              const float* __restrict__ Dvec,
              const unsigned short* __restrict__ ow_bf,
              float* __restrict__ out)
{
    __shared__ __align__(16) char sm[KB_LDS];
    float* dbc = (float*)(sm + KB_DBC);

    const int tid = threadIdx.x;
    const int b   = blockIdx.x;
    const int wv  = tid >> 6;
    const int ln  = tid & 63;
    const int lr  = ln & 15;
    const int lg  = ln >> 4;

    // ---- P0: stage xproj_w (pre-converted, pre-padded) -> WB
    for (int idx = tid; idx < 768; idx += 256)
        *(uint4*)(sm + KB_WB + (idx&15)*784 + (idx>>4)*16) =
            *(const uint4*)(xpw_bf + idx*8);

    // ---- P1: causal conv (4-tap FIR, fully parallel over (t, c8)) + SiLU
    for (int idx = tid; idx < 1280; idx += 256) {
        const int t = idx >> 4, c8 = idx & 15;
        uint4 r = make_uint4(0u, 0u, 0u, 0u);
        if (t < 77) {
            const unsigned short* base = u_raw + (size_t)b * TL * TDI + c8 * 8;
            uint4 rows[4];
            #pragma unroll
            for (int j = 0; j < 4; ++j) {
                const int tt = t - 3 + j;
                rows[j] = (tt >= 0) ? *(const uint4*)(base + (size_t)tt * TDI)
                                    : make_uint4(0u, 0u, 0u, 0u);
            }
            #pragma unroll
            for (int e = 0; e < 8; ++e) {
                const int c = c8*8 + e;
                const float4 cw = *(const float4*)(conv_w + c*4);
                const float x0 = bf2f(((const unsigned short*)&rows[0])[e]);
                const float x1 = bf2f(((const unsigned short*)&rows[1])[e]);
                const float x2 = bf2f(((const unsigned short*)&rows[2])[e]);
                const float x3 = bf2f(((const unsigned short*)&rows[3])[e]);
                float v = fmaf(cw.x, x0, fmaf(cw.y, x1,
                          fmaf(cw.z, x2, fmaf(cw.w, x3, conv_b[c]))));
                v = v * fsig(v);
                ((unsigned short*)&r)[e] = f2bf(v);
            }
        }
        *(uint4*)(sm + KB_U + c8*1296 + t*16) = r;   // rows 77..79 zeroed
    }
    __syncthreads();

    // ---- P2: xproj MFMA  dbc[t][n], M=80 N=48 K=128 (15 tiles / 4 waves)
    for (int tile = wv; tile < 15; tile += 4) {
        const int mt = tile / 3, nt = tile % 3;
        f32x4 acc = (f32x4){0.f, 0.f, 0.f, 0.f};
        #pragma unroll
        for (int ks = 0; ks < 4; ++ks) {
            const bf16x8 a = *(const bf16x8*)(sm + KB_U  + (ks*4+lg)*1296 + (mt*16+lr)*16);
            const bf16x8 bb = *(const bf16x8*)(sm + KB_WB + (ks*4+lg)*784  + (nt*16+lr)*16);
            acc = __builtin_amdgcn_mfma_f32_16x16x32_bf16(a, bb, acc, 0, 0, 0);
        }
        const int n = nt*16 + lr;
        if (n < 36) {
            #pragma unroll
            for (int r = 0; r < 4; ++r)
                dbc[(mt*16 + lg*4 + r)*40 + n] = acc[r];
        }
    }
    __syncthreads();

    // ---- P3: selective scan (thread pair per channel; y overwrites u)
    {
        const int d  = tid >> 1;
        const int sh = tid & 1;
        const int sb = sh * 8;
        float Av[8];
        #pragma unroll
        for (int i = 0; i < 8; ++i) Av[i] = -__expf(A_log[d*16 + sb + i]);
        const float4 dtw = *(const float4*)(dtproj_w + d*4);
        const float dtb = dtproj_b[d];
        const float Dd  = Dvec[d];
        char* uptr = sm + KB_U + (d>>3)*1296 + (d&7)*2;
        float h[8];
        #pragma unroll
        for (int i = 0; i < 8; ++i) h[i] = 0.f;

        for (int t = 0; t < TL; ++t) {
            const float4 dtv = *(const float4*)&dbc[t*40];
            const float pre = fmaf(dtv.x, dtw.x, fmaf(dtv.y, dtw.y,
                              fmaf(dtv.z, dtw.z, fmaf(dtv.w, dtw.w, dtb))));
            float dl = __logf(1.0f + __expf(pre));
            if (pre > 20.0f) dl = pre;
            const float ut = bf2f(*(unsigned short*)(uptr + t*16));
            const float du = dl * ut;
            const float4 Bv0 = *(const float4*)&dbc[t*40 + 4  + sb];
            const float4 Bv1 = *(const float4*)&dbc[t*40 + 8  + sb];
            const float4 Cv0 = *(const float4*)&dbc[t*40 + 20 + sb];
            const float4 Cv1 = *(const float4*)&dbc[t*40 + 24 + sb];
            const float Bs[8] = {Bv0.x,Bv0.y,Bv0.z,Bv0.w, Bv1.x,Bv1.y,Bv1.z,Bv1.w};
            const float Cs[8] = {Cv0.x,Cv0.y,Cv0.z,Cv0.w, Cv1.x,Cv1.y,Cv1.z,Cv1.w};
            float ys = 0.f;
            #pragma unroll
            for (int i = 0; i < 8; ++i) {
                const float dA = __expf(dl * Av[i]);
                h[i] = fmaf(h[i], dA, du * Bs[i]);
                ys = fmaf(h[i], Cs[i], ys);
            }
            ys += __shfl_xor(ys, 1, 64);
            if (!sh)
                *(unsigned short*)(uptr + t*16) = f2bf(fmaf(Dd, ut, ys));
        }
    }
    __syncthreads();

    // ---- P4: stage out_w (pre-converted, over dead xw) + gate y *= silu(z)
    for (int idx = tid; idx < 1024; idx += 256)
        *(uint4*)(sm + KB_WB + (idx&15)*1040 + (idx>>4)*16) =
            *(const uint4*)(ow_bf + idx*8);
    for (int idx = tid; idx < 1232; idx += 256) {     // 77*16 (t, d8)
        const int t = idx >> 4, d8 = idx & 15;
        const uint4 zv = *(const uint4*)(z_in + ((size_t)b * TL + t) * TDI + d8*8);
        uint4 uv = *(uint4*)(sm + KB_U + d8*1296 + t*16);
        #pragma unroll
        for (int e = 0; e < 8; ++e) {
            const float z = bf2f(((const unsigned short*)&zv)[e]);
            const float y = bf2f(((const unsigned short*)&uv)[e]);
            ((unsigned short*)&uv)[e] = f2bf(y * (z * fsig(z)));
        }
        *(uint4*)(sm + KB_U + d8*1296 + t*16) = uv;
    }
    __syncthreads();

    // ---- P5: outproj MFMA  out[t][w], M=80 N=64 K=128 (20 tiles / 4 waves)
    for (int tile = wv; tile < 20; tile += 4) {
        const int mt = tile >> 2, nt = tile & 3;
        f32x4 acc = (f32x4){0.f, 0.f, 0.f, 0.f};
        #pragma unroll
        for (int ks = 0; ks < 4; ++ks) {
            const bf16x8 a = *(const bf16x8*)(sm + KB_U  + (ks*4+lg)*1296 + (mt*16+lr)*16);
            const bf16x8 bb = *(const bf16x8*)(sm + KB_WB + (ks*4+lg)*1040 + (nt*16+lr)*16);
            acc = __builtin_amdgcn_mfma_f32_16x16x32_bf16(a, bb, acc, 0, 0, 0);
        }
        #pragma unroll
        for (int r = 0; r < 4; ++r) {
            const int t = mt*16 + lg*4 + r;
            if (t < 77)
                out[((size_t)b * TL + t) * 64 + nt*16 + lr] = acc[r];
        }
    }
}

// =====================================================================
extern "C" void kernel_launch(void* const* d_in, const int* in_sizes, int n_in,
                              void* d_out, int out_size, void* d_ws, size_t ws_size,
                              hipStream_t stream)
{
    const float* enc      = (const float*)d_in[0];
    const float* dec_w    = (const float*)d_in[1];
    const float* dec_b    = (const float*)d_in[2];
    const float* in_w     = (const float*)d_in[3];
    const float* conv_w   = (const float*)d_in[4];
    const float* conv_b   = (const float*)d_in[5];
    const float* xproj_w  = (const float*)d_in[6];
    const float* dtproj_w = (const float*)d_in[7];
    const float* dtproj_b = (const float*)d_in[8];
    const float* A_log    = (const float*)d_in[9];
    const float* Dvec     = (const float*)d_in[10];
    const float* out_w    = (const float*)d_in[11];
    float* out = (float*)d_out;

    // ws layout (bytes): u_raw 40,370,176 | z 40,370,176 | enc_bf 524,288 |
    // dec_bf 1,261,568 | inw_bf 32,768 | xpw_bf 12,288 | ow_bf 16,384  (~82.6 MB)
    unsigned short* u_raw  = (unsigned short*)d_ws;
    unsigned short* z_buf  = u_raw  + (size_t)TB * TL * TDI;
    unsigned short* enc_bf = z_buf  + (size_t)TB * TL * TDI;
    unsigned short* dec_bf = enc_bf + (size_t)2048 * 128;
    unsigned short* inw_bf = dec_bf + (size_t)4928 * 128;
    unsigned short* xpw_bf = inw_bf + (size_t)256 * 64;
    unsigned short* ow_bf  = xpw_bf + (size_t)48 * 128;

    kw_convert<<<dim3(451), dim3(256), 0, stream>>>(
        enc, dec_w, in_w, xproj_w, out_w, enc_bf, dec_bf, inw_bf, xpw_bf, ow_bf);

    dim3 gA(TB / 64, TL);
    ka_dec_inproj<<<gA, dim3(256), 0, stream>>>(enc_bf, dec_bf, dec_b, inw_bf,
                                                u_raw, z_buf);
    kb_mamba<<<dim3(TB), dim3(256), 0, stream>>>(u_raw, z_buf, conv_w, conv_b,
                                                 xpw_bf, dtproj_w, dtproj_b,
                                                 A_log, Dvec, ow_bf, out);
}

// Round 10
// 231.235 us; speedup vs baseline: 1.9767x; 1.0877x over previous
//
#include <hip/hip_runtime.h>
#include <cstdint>
#include <cstddef>

#define TB 2048
#define TL 77
#define TDI 128

typedef __bf16 bf16x8 __attribute__((ext_vector_type(8)));
typedef float f32x4 __attribute__((ext_vector_type(4)));

// ---------- helpers ----------
__device__ __forceinline__ float bf2f(unsigned short h) {
    unsigned int u = ((unsigned int)h) << 16;
    float f; __builtin_memcpy(&f, &u, 4); return f;
}
__device__ __forceinline__ unsigned short f2bf(float f) {
    unsigned int u; __builtin_memcpy(&u, &f, 4);
    u = (u + 0x7fffu + ((u >> 16) & 1u)) >> 16;
    return (unsigned short)u;
}
__device__ __forceinline__ float fsig(float x) {
    return __builtin_amdgcn_rcpf(1.0f + __expf(-x));
}
__device__ __forceinline__ uint4 pack8(float4 a, float4 b) {
    uint4 r;
    r.x = (unsigned int)f2bf(a.x) | ((unsigned int)f2bf(a.y) << 16);
    r.y = (unsigned int)f2bf(a.z) | ((unsigned int)f2bf(a.w) << 16);
    r.z = (unsigned int)f2bf(b.x) | ((unsigned int)f2bf(b.y) << 16);
    r.w = (unsigned int)f2bf(b.z) | ((unsigned int)f2bf(b.w) << 16);
    return r;
}

// =====================================================================
// KW: one-shot f32 -> bf16 conversion.
//   enc_bf / dec_bf : row-major chunked (consumed via LDS staging in KA)
//   inw_t  : [8 kc][256 c][8]   (B-fragments read direct from L2)
//   xpw_t  : [16 kc][48 n][8]   zero-padded n>=36
//   ow_t   : [16 kc][64 n][8]
// chunk counts: enc 32768 | dec 78848 | inw 2048 | xpw 768 | ow 1024
// total 115456 = 451 * 256
// =====================================================================
__global__ __launch_bounds__(256)
void kw_convert(const float* __restrict__ enc, const float* __restrict__ dec_w,
                const float* __restrict__ in_w, const float* __restrict__ xproj_w,
                const float* __restrict__ out_w,
                unsigned short* __restrict__ enc_bf, unsigned short* __restrict__ dec_bf,
                unsigned short* __restrict__ inw_t, unsigned short* __restrict__ xpw_t,
                unsigned short* __restrict__ ow_t)
{
    int rel = blockIdx.x * 256 + threadIdx.x;
    const float* src = nullptr;
    unsigned short* dst;
    if (rel < 32768) { src = enc + (size_t)rel * 8; dst = enc_bf + (size_t)rel * 8; }
    else if ((rel -= 32768) < 78848) { src = dec_w + (size_t)rel * 8; dst = dec_bf + (size_t)rel * 8; }
    else if ((rel -= 78848) < 2048) {          // in_w chunk (c=rel>>3, kc=rel&7)
        src = in_w + (size_t)rel * 8;
        dst = inw_t + (size_t)(rel & 7) * 2048 + (rel >> 3) * 8;
    }
    else if ((rel -= 2048) < 768) {            // xproj chunk (n=rel>>4, kc=rel&15)
        dst = xpw_t + (size_t)(rel & 15) * 384 + (rel >> 4) * 8;
        if ((rel >> 4) < 36) src = xproj_w + (size_t)rel * 8;
    }
    else { rel -= 768;                         // out_w chunk (n=rel>>4, kc=rel&15)
        src = out_w + (size_t)rel * 8;
        dst = ow_t + (size_t)(rel & 15) * 512 + (rel >> 4) * 8;
    }
    uint4 v = make_uint4(0u, 0u, 0u, 0u);
    if (src) v = pack8(*(const float4*)src, *(const float4*)(src + 4));
    *(uint4*)dst = v;
}

// =====================================================================
// KA: x = enc @ dec_w.T + dec_b  ->  xz = x @ in_w.T  (bf16 MFMA)
// in_w B-fragments stream from L2 (inw_t); LDS 41.1 KB -> 3 blocks/CU.
// =====================================================================
#define KA_ENC 0            // [16 kc][65 pad][8]  stride 1040  (16640 B)
#define KA_DEC 16640        // [16 kc][65 pad][8]  stride 1040  (16640 B)
#define KA_TRS 0            // transpose buf [64 m][528 B] (33792 B, overlays ENC+DEC)
#define KA_R2  33792        // x  [8 kc][65 pad][8] stride 1040  (8320 B)
#define KA_LDS 42112

__global__ __launch_bounds__(256, 3)
void ka_dec_inproj(const unsigned short* __restrict__ enc_bf,
                   const unsigned short* __restrict__ dec_bf,
                   const float* __restrict__ dec_b,
                   const unsigned short* __restrict__ inw_t,
                   unsigned short* __restrict__ u_raw,
                   unsigned short* __restrict__ z_out)
{
    __shared__ __align__(16) char sm[KA_LDS];

    const int tid = threadIdx.x;
    const int m0  = blockIdx.x * 64;
    const int l   = blockIdx.y;
    const int wv  = tid >> 6;         // wave = m-tile
    const int ln  = tid & 63;
    const int lr  = ln & 15;
    const int lg  = ln >> 4;

    // ---- P0: stage enc tile + dec_w tile (16B copies)
    {
        const unsigned short* ebase = enc_bf + (size_t)m0 * 128;
        const unsigned short* dbase = dec_bf + (size_t)l * 64 * 128;
        for (int idx = tid; idx < 1024; idx += 256) {
            const int m = idx >> 4, kc = idx & 15;
            *(uint4*)(sm + KA_ENC + kc*1040 + m*16) = *(const uint4*)(ebase + idx*8);
            *(uint4*)(sm + KA_DEC + kc*1040 + m*16) = *(const uint4*)(dbase + idx*8);
        }
    }
    __syncthreads();

    // ---- P1: GEMM1  x[m][w], M=64 N=64 K=128
    f32x4 acc1[4];
    #pragma unroll
    for (int nt = 0; nt < 4; ++nt) acc1[nt] = (f32x4){0.f, 0.f, 0.f, 0.f};
    #pragma unroll
    for (int ks = 0; ks < 4; ++ks) {
        const bf16x8 a = *(const bf16x8*)(sm + KA_ENC + (ks*4+lg)*1040 + (wv*16+lr)*16);
        #pragma unroll
        for (int nt = 0; nt < 4; ++nt) {
            const bf16x8 bb = *(const bf16x8*)(sm + KA_DEC + (ks*4+lg)*1040 + (nt*16+lr)*16);
            acc1[nt] = __builtin_amdgcn_mfma_f32_16x16x32_bf16(a, bb, acc1[nt], 0, 0, 0);
        }
    }

    // ---- P2: x (+bias) -> R2 k-chunked bf16 (wave-local rows)
    #pragma unroll
    for (int nt = 0; nt < 4; ++nt) {
        const int w = nt*16 + lr;
        const float bias = dec_b[l*64 + w];
        #pragma unroll
        for (int r = 0; r < 4; ++r) {
            const int m = wv*16 + lg*4 + r;
            *(unsigned short*)(sm + KA_R2 + (w>>3)*1040 + m*16 + (w&7)*2) =
                f2bf(acc1[nt][r] + bias);
        }
    }

    // ---- P3: in_proj  xz[m][c], M=64 N=256 K=64 (B direct from L2)
    f32x4 acc2[16];
    #pragma unroll
    for (int nt = 0; nt < 16; ++nt) acc2[nt] = (f32x4){0.f, 0.f, 0.f, 0.f};
    #pragma unroll
    for (int ks = 0; ks < 2; ++ks) {
        const bf16x8 a = *(const bf16x8*)(sm + KA_R2 + (ks*4+lg)*1040 + (wv*16+lr)*16);
        #pragma unroll
        for (int nt = 0; nt < 16; ++nt) {
            const bf16x8 bb = *(const bf16x8*)(inw_t + (ks*4+lg)*2048 + (nt*16+lr)*8);
            acc2[nt] = __builtin_amdgcn_mfma_f32_16x16x32_bf16(a, bb, acc2[nt], 0, 0, 0);
        }
    }
    __syncthreads();   // all waves done with ENC/DEC/R2 (TRS overlays)

    // ---- P4: xz -> transpose buffer [m][256 c] bf16, stride 528 B
    #pragma unroll
    for (int nt = 0; nt < 16; ++nt) {
        const int c = nt*16 + lr;
        #pragma unroll
        for (int r = 0; r < 4; ++r) {
            const int m = wv*16 + lg*4 + r;
            *(unsigned short*)(sm + KA_TRS + m*528 + c*2) = f2bf(acc2[nt][r]);
        }
    }
    __syncthreads();

    // ---- P5: coalesced global store (uint4 = 8 bf16)
    for (int idx = tid; idx < 2048; idx += 256) {
        const int m = idx >> 5, ch = idx & 31;
        const uint4 v = *(const uint4*)(sm + KA_TRS + m*528 + ch*16);
        const size_t base = ((size_t)(m0 + m) * TL + l) * TDI;
        if (ch < 16) *(uint4*)(u_raw + base + ch*8) = v;
        else         *(uint4*)(z_out + base + (ch-16)*8) = v;
    }
}

// =====================================================================
// KB: conv+silu -> xproj(MFMA, B from L2) -> scan (structured-A fast
//     path) -> gate -> outproj(MFMA, B from L2). LDS 30.8 KB -> 5 bl/CU.
// =====================================================================
#define KB_U   0            // u/y [16 kc][80 t][8] stride 1280  (20480 B)
#define KB_DBC 20480        // dbc [77 t][36] f32               (11088 B)
#define KB_LDS 31568

__global__ __launch_bounds__(256, 5)
void kb_mamba(const unsigned short* __restrict__ u_raw,
              const unsigned short* __restrict__ z_in,
              const float* __restrict__ conv_w,
              const float* __restrict__ conv_b,
              const unsigned short* __restrict__ xpw_t,
              const float* __restrict__ dtproj_w,
              const float* __restrict__ dtproj_b,
              const float* __restrict__ A_log,
              const float* __restrict__ Dvec,
              const unsigned short* __restrict__ ow_t,
              float* __restrict__ out)
{
    __shared__ __align__(16) char sm[KB_LDS];
    float* dbc = (float*)(sm + KB_DBC);

    const int tid = threadIdx.x;
    const int b   = blockIdx.x;
    const int wv  = tid >> 6;
    const int ln  = tid & 63;
    const int lr  = ln & 15;
    const int lg  = ln >> 4;

    // ---- P1: causal conv (4-tap FIR, parallel over (t, c8)) + SiLU
    for (int idx = tid; idx < 1280; idx += 256) {
        const int t = idx >> 4, c8 = idx & 15;
        uint4 r = make_uint4(0u, 0u, 0u, 0u);
        if (t < 77) {
            const unsigned short* base = u_raw + (size_t)b * TL * TDI + c8 * 8;
            uint4 rows[4];
            #pragma unroll
            for (int j = 0; j < 4; ++j) {
                const int tt = t - 3 + j;
                rows[j] = (tt >= 0) ? *(const uint4*)(base + (size_t)tt * TDI)
                                    : make_uint4(0u, 0u, 0u, 0u);
            }
            #pragma unroll
            for (int e = 0; e < 8; ++e) {
                const int c = c8*8 + e;
                const float4 cw = *(const float4*)(conv_w + c*4);
                const float x0 = bf2f(((const unsigned short*)&rows[0])[e]);
                const float x1 = bf2f(((const unsigned short*)&rows[1])[e]);
                const float x2 = bf2f(((const unsigned short*)&rows[2])[e]);
                const float x3 = bf2f(((const unsigned short*)&rows[3])[e]);
                float v = fmaf(cw.x, x0, fmaf(cw.y, x1,
                          fmaf(cw.z, x2, fmaf(cw.w, x3, conv_b[c]))));
                v = v * fsig(v);
                ((unsigned short*)&r)[e] = f2bf(v);
            }
        }
        *(uint4*)(sm + KB_U + c8*1280 + t*16) = r;   // rows 77..79 zeroed
    }
    __syncthreads();

    // ---- P2: xproj MFMA  dbc[t][n], M=80 N=48 K=128 (B from L2)
    for (int tile = wv; tile < 15; tile += 4) {
        const int mt = tile / 3, nt = tile % 3;
        f32x4 acc = (f32x4){0.f, 0.f, 0.f, 0.f};
        #pragma unroll
        for (int ks = 0; ks < 4; ++ks) {
            const bf16x8 a = *(const bf16x8*)(sm + KB_U + (ks*4+lg)*1280 + (mt*16+lr)*16);
            const bf16x8 bb = *(const bf16x8*)(xpw_t + (ks*4+lg)*384 + (nt*16+lr)*8);
            acc = __builtin_amdgcn_mfma_f32_16x16x32_bf16(a, bb, acc, 0, 0, 0);
        }
        const int n = nt*16 + lr;
        if (n < 36) {
            #pragma unroll
            for (int r = 0; r < 4; ++r) {
                const int row = mt*16 + lg*4 + r;
                if (row < 77) dbc[row*36 + n] = acc[r];
            }
        }
    }
    __syncthreads();

    // ---- P3: selective scan (pair per channel; structured-A fast path)
    {
        const int d  = tid >> 1;
        const int sh = tid & 1;
        const int sb = sh * 8;
        float Av[8];
        bool ok = true;
        #pragma unroll
        for (int i = 0; i < 8; ++i) {
            Av[i] = -__expf(A_log[d*16 + sb + i]);
            const float n = (float)(sb + i + 1);
            ok = ok && (__builtin_fabsf(Av[i] + n) <= 1e-4f * n);
        }
        const bool structured = __all(ok);
        const float4 dtw = *(const float4*)(dtproj_w + d*4);
        const float dtb = dtproj_b[d];
        const float Dd  = Dvec[d];
        char* uptr = sm + KB_U + (d>>3)*1280 + (d&7)*2;
        float h[8];
        #pragma unroll
        for (int i = 0; i < 8; ++i) h[i] = 0.f;

        if (structured) {
            // dA_s = r^(s+1), r = exp(-delta); A[d][s] = -(s+1) verified
            for (int t = 0; t < TL; ++t) {
                const float4 dtv = *(const float4*)&dbc[t*36];
                const float pre = fmaf(dtv.x, dtw.x, fmaf(dtv.y, dtw.y,
                                  fmaf(dtv.z, dtw.z, fmaf(dtv.w, dtw.w, dtb))));
                float dl = __logf(1.0f + __expf(pre));
                if (pre > 20.0f) dl = pre;
                const float ut = bf2f(*(unsigned short*)(uptr + t*16));
                const float du = dl * ut;
                const float4 Bv0 = *(const float4*)&dbc[t*36 + 4  + sb];
                const float4 Bv1 = *(const float4*)&dbc[t*36 + 8  + sb];
                const float4 Cv0 = *(const float4*)&dbc[t*36 + 20 + sb];
                const float4 Cv1 = *(const float4*)&dbc[t*36 + 24 + sb];
                const float Bs[8] = {Bv0.x,Bv0.y,Bv0.z,Bv0.w, Bv1.x,Bv1.y,Bv1.z,Bv1.w};
                const float Cs[8] = {Cv0.x,Cv0.y,Cv0.z,Cv0.w, Cv1.x,Cv1.y,Cv1.z,Cv1.w};
                const float r1 = __expf(-dl);
                const float r2 = r1*r1, r3 = r1*r2, r4 = r2*r2;
                const float r5 = r1*r4, r6 = r2*r4, r7 = r3*r4, r8 = r4*r4;
                const float base = sh ? r8 : 1.0f;
                const float p[8] = {r1, r2, r3, r4, r5, r6, r7, r8};
                float ys = 0.f;
                #pragma unroll
                for (int i = 0; i < 8; ++i) {
                    const float dA = p[i] * base;
                    h[i] = fmaf(h[i], dA, du * Bs[i]);
                    ys = fmaf(h[i], Cs[i], ys);
                }
                ys += __shfl_xor(ys, 1, 64);
                if (!sh)
                    *(unsigned short*)(uptr + t*16) = f2bf(fmaf(Dd, ut, ys));
            }
        } else {
            for (int t = 0; t < TL; ++t) {
                const float4 dtv = *(const float4*)&dbc[t*36];
                const float pre = fmaf(dtv.x, dtw.x, fmaf(dtv.y, dtw.y,
                                  fmaf(dtv.z, dtw.z, fmaf(dtv.w, dtw.w, dtb))));
                float dl = __logf(1.0f + __expf(pre));
                if (pre > 20.0f) dl = pre;
                const float ut = bf2f(*(unsigned short*)(uptr + t*16));
                const float du = dl * ut;
                const float4 Bv0 = *(const float4*)&dbc[t*36 + 4  + sb];
                const float4 Bv1 = *(const float4*)&dbc[t*36 + 8  + sb];
                const float4 Cv0 = *(const float4*)&dbc[t*36 + 20 + sb];
                const float4 Cv1 = *(const float4*)&dbc[t*36 + 24 + sb];
                const float Bs[8] = {Bv0.x,Bv0.y,Bv0.z,Bv0.w, Bv1.x,Bv1.y,Bv1.z,Bv1.w};
                const float Cs[8] = {Cv0.x,Cv0.y,Cv0.z,Cv0.w, Cv1.x,Cv1.y,Cv1.z,Cv1.w};
                float ys = 0.f;
                #pragma unroll
                for (int i = 0; i < 8; ++i) {
                    const float dA = __expf(dl * Av[i]);
                    h[i] = fmaf(h[i], dA, du * Bs[i]);
                    ys = fmaf(h[i], Cs[i], ys);
                }
                ys += __shfl_xor(ys, 1, 64);
                if (!sh)
                    *(unsigned short*)(uptr + t*16) = f2bf(fmaf(Dd, ut, ys));
            }
        }
    }
    __syncthreads();

    // ---- P4: gate y *= silu(z)
    for (int idx = tid; idx < 1232; idx += 256) {     // 77*16 (t, d8)
        const int t = idx >> 4, d8 = idx & 15;
        const uint4 zv = *(const uint4*)(z_in + ((size_t)b * TL + t) * TDI + d8*8);
        uint4 uv = *(uint4*)(sm + KB_U + d8*1280 + t*16);
        #pragma unroll
        for (int e = 0; e < 8; ++e) {
            const float z = bf2f(((const unsigned short*)&zv)[e]);
            const float y = bf2f(((const unsigned short*)&uv)[e]);
            ((unsigned short*)&uv)[e] = f2bf(y * (z * fsig(z)));
        }
        *(uint4*)(sm + KB_U + d8*1280 + t*16) = uv;
    }
    __syncthreads();

    // ---- P5: outproj MFMA  out[t][w], M=80 N=64 K=128 (B from L2)
    for (int tile = wv; tile < 20; tile += 4) {
        const int mt = tile >> 2, nt = tile & 3;
        f32x4 acc = (f32x4){0.f, 0.f, 0.f, 0.f};
        #pragma unroll
        for (int ks = 0; ks < 4; ++ks) {
            const bf16x8 a = *(const bf16x8*)(sm + KB_U + (ks*4+lg)*1280 + (mt*16+lr)*16);
            const bf16x8 bb = *(const bf16x8*)(ow_t + (ks*4+lg)*512 + (nt*16+lr)*8);
            acc = __builtin_amdgcn_mfma_f32_16x16x32_bf16(a, bb, acc, 0, 0, 0);
        }
        #pragma unroll
        for (int r = 0; r < 4; ++r) {
            const int t = mt*16 + lg*4 + r;
            if (t < 77)
                out[((size_t)b * TL + t) * 64 + nt*16 + lr] = acc[r];
        }
    }
}

// =====================================================================
extern "C" void kernel_launch(void* const* d_in, const int* in_sizes, int n_in,
                              void* d_out, int out_size, void* d_ws, size_t ws_size,
                              hipStream_t stream)
{
    const float* enc      = (const float*)d_in[0];
    const float* dec_w    = (const float*)d_in[1];
    const float* dec_b    = (const float*)d_in[2];
    const float* in_w     = (const float*)d_in[3];
    const float* conv_w   = (const float*)d_in[4];
    const float* conv_b   = (const float*)d_in[5];
    const float* xproj_w  = (const float*)d_in[6];
    const float* dtproj_w = (const float*)d_in[7];
    const float* dtproj_b = (const float*)d_in[8];
    const float* A_log    = (const float*)d_in[9];
    const float* Dvec     = (const float*)d_in[10];
    const float* out_w    = (const float*)d_in[11];
    float* out = (float*)d_out;

    unsigned short* u_raw  = (unsigned short*)d_ws;
    unsigned short* z_buf  = u_raw  + (size_t)TB * TL * TDI;
    unsigned short* enc_bf = z_buf  + (size_t)TB * TL * TDI;
    unsigned short* dec_bf = enc_bf + (size_t)2048 * 128;
    unsigned short* inw_t  = dec_bf + (size_t)4928 * 128;
    unsigned short* xpw_t  = inw_t  + (size_t)8 * 2048;
    unsigned short* ow_t   = xpw_t  + (size_t)16 * 384;

    kw_convert<<<dim3(451), dim3(256), 0, stream>>>(
        enc, dec_w, in_w, xproj_w, out_w, enc_bf, dec_bf, inw_t, xpw_t, ow_t);

    dim3 gA(TB / 64, TL);
    ka_dec_inproj<<<gA, dim3(256), 0, stream>>>(enc_bf, dec_bf, dec_b, inw_t,
                                                u_raw, z_buf);
    kb_mamba<<<dim3(TB), dim3(256), 0, stream>>>(u_raw, z_buf, conv_w, conv_b,
                                                 xpw_t, dtproj_w, dtproj_b,
                                                 A_log, Dvec, ow_t, out);
}